// Round 11
// baseline (167.651 us; speedup 1.0000x reference)
//
#include <hip/hip_runtime.h>
#include <hip/hip_bf16.h>
#include <float.h>

#define BATCH    32
#define NPRIORS  8732
#define NT       137            // tiles of 64 priors
#define NPAD     (NT * 64)      // 8768 (padded prior count)
#define NV4T     (NPAD / 4)     // 2192 float4 per class column
#define NCLASSES 81
#define NC1      80             // classes excluding background
#define TOPK     100
#define MAXDET   100
#define FLATC    (NC1 * TOPK)   // 8000
#define FV4      2000           // FLATC / 4
#define NCAND    512
#define NBIN     1024           // (bits>>18) - 3040 : exp + 5 mantissa bits
#define BINOFF   3040

// ---------------------------------------------------------------------------
// Kernel 1: softmax over classes + TILED transpose.  (v5 verbatim — proven)
// Also zeroes the per-batch completion counters for kernel 2's last-block
// final-topk (stream order guarantees visibility before kernel 2 starts).
// scores_t layout: [B][NT][NC1][64] (tile-major).
// ---------------------------------------------------------------------------
__global__ __launch_bounds__(256) void softmax_transpose_kernel(
    const float* __restrict__ logits, float* __restrict__ scores_t,
    unsigned int* __restrict__ done) {
  if (blockIdx.x < BATCH && threadIdx.x == 0) done[blockIdx.x] = 0u;

  int b = blockIdx.x / NT;
  int tile = blockIdx.x - b * NT;
  int n0 = tile * 64;
  int rows = min(64, NPRIORS - n0);  // 64 or 28

  int t = threadIdx.x;
  int r = t >> 2;   // row within tile
  int q = t & 3;

  __shared__ __align__(16) float lds[NC1 * 80];  // 25.6 KB transpose buffer

  const bool live = (r < rows);

  float v[21];
  float s = 0.f;
  if (live) {
    const float* rowp = logits + ((size_t)b * NPRIORS + n0 + r) * NCLASSES;
#pragma unroll
    for (int k = 0; k < 20; ++k) v[k] = rowp[q + (k << 2)];
    v[20] = (q == 0) ? rowp[80] : -FLT_MAX;

    float m = -FLT_MAX;
#pragma unroll
    for (int k = 0; k < 20; ++k) m = fmaxf(m, v[k]);
    if (q == 0) m = fmaxf(m, v[20]);
    m = fmaxf(m, __shfl_xor(m, 1));
    m = fmaxf(m, __shfl_xor(m, 2));

#pragma unroll
    for (int k = 0; k < 20; ++k) {
      v[k] = expf(v[k] - m);
      s += v[k];
    }
    if (q == 0) {
      v[20] = expf(v[20] - m);
      s += v[20];
    }
    s += __shfl_xor(s, 1);
    s += __shfl_xor(s, 2);

    // transposed store into LDS, column stride 80 (<=2-way banks)
#pragma unroll
    for (int k = 0; k < 20; ++k) {
      int c = q + (k << 2);
      if (c >= 1) lds[(c - 1) * 80 + r] = v[k] / s;
    }
    if (q == 0) lds[79 * 80 + r] = v[20] / s;
  } else {
    // pad slots must be +0.0 (bits==0 -> never histogrammed/selected)
#pragma unroll
    for (int k = 0; k < 20; ++k) {
      int c = q + (k << 2);
      if (c >= 1) lds[(c - 1) * 80 + r] = 0.f;
    }
    if (q == 0) lds[79 * 80 + r] = 0.f;
  }
  __syncthreads();  // transposed tile ready

  // ---- flush: 1280 contiguous float4 stores
  float4* d4 = (float4*)(scores_t + (size_t)(b * NT + tile) * (NC1 * 64));
#pragma unroll
  for (int i = 0; i < 5; ++i) {
    int o4 = t + (i << 8);       // 0..1279
    int c = o4 >> 4;             // class column 0..79
    int j = o4 & 15;             // float4 within column
    d4[o4] = *(const float4*)&lds[c * 80 + (j << 2)];
  }
}

// ---------------------------------------------------------------------------
// Box decode (identical float expressions to the reference)
// ---------------------------------------------------------------------------
__device__ __forceinline__ float4 decode_box(float4 l, float4 p) {
  float cx = l.x * 0.1f * p.z + p.x;
  float cy = l.y * 0.1f * p.w + p.y;
  float w  = expf(l.z * 0.2f) * p.z;
  float h  = expf(l.w * 0.2f) * p.w;
  return make_float4(cx - w * 0.5f, cy - h * 0.5f, cx + w * 0.5f,
                     cy + h * 0.5f);
}

__device__ __forceinline__ unsigned long long cex(unsigned long long key,
                                                  unsigned long long p,
                                                  bool up, bool low) {
  return (up == low) ? (key < p ? key : p) : (key > p ? key : p);
}

// ---------------------------------------------------------------------------
// Kernel 2: block-per-(batch,class) top-100 select + FUSED NMS + (last block
// per batch) FUSED per-image final top-100.
// v12 = v11 + last-block pattern: after writing s_k/b_k, each block does a
//       release fence + device-scope atomicAdd(done[b]); the 80th block for
//       its batch runs the old kernel-4 logic in place (two-pass, register-
//       light, reusing the hist/cand LDS), writing `out` directly.
// ---------------------------------------------------------------------------
__global__ __launch_bounds__(256, 8) void topk_nms_kernel(
    const float* __restrict__ scores_t, const float* __restrict__ loc,
    const float* __restrict__ priors, float* __restrict__ s_k,
    float* __restrict__ b_k, float* __restrict__ out,
    unsigned int* __restrict__ done) {
  const int bc = blockIdx.x;
  const int b = bc / NC1;
  const int c = bc - b * NC1;
  const int t = threadIdx.x;
  const int lane = t & 63;
  const int w = t >> 6;

  __shared__ __align__(16) unsigned int hist[NBIN * 2];     // 8 KB, 2 replicas
  __shared__ __align__(16) unsigned long long cand[NCAND];  // 4 KB
  __shared__ __align__(16) unsigned long long skey[TOPK];   // 800 B sorted keys
  __shared__ int s_cnt, s_cut, wtot[4], s_last;

  const float4* s4 = (const float4*)scores_t;
  const size_t base4 = (size_t)b * (NT * NC1 * 16) + (size_t)c * 16;

  // ---- single global read: 9 float4 = 36 floats into registers
  float va[36];
#pragma unroll
  for (int i = 0; i < 9; ++i) {
    int p = t + (i << 8);
    float4 v = make_float4(0.f, 0.f, 0.f, 0.f);
    if (p < NV4T) v = s4[base4 + (size_t)(p >> 4) * (NC1 * 16) + (p & 15)];
    va[4 * i + 0] = v.x; va[4 * i + 1] = v.y;
    va[4 * i + 2] = v.z; va[4 * i + 3] = v.w;
  }
#pragma unroll
  for (int j = 0; j < 36; ++j) asm volatile("" : "+v"(va[j]));  // pin live

  // ---- zero hist (2048 words) + init cand + counters
  uint4* h4 = (uint4*)hist;
  const uint4 z4 = make_uint4(0u, 0u, 0u, 0u);
  h4[t] = z4;
  h4[t + 256] = z4;
  cand[t] = ~0ull;
  cand[t + 256] = ~0ull;
  if (t == 0) { s_cnt = 0; s_cut = 0; }
  __syncthreads();  // B0

  // ---- coarse histogram from registers (skip zeros: padding & exact-0)
#pragma unroll
  for (int j = 0; j < 36; ++j) {
    unsigned int bits = __float_as_uint(va[j]);
    if (bits != 0u) {
      int bin = (int)(bits >> 18) - BINOFF;
      bin = max(0, min(NBIN - 1, bin));
      atomicAdd(&hist[(bin << 1) | (lane & 1)], 1u);
    }
  }
  __syncthreads();  // B1

  // ---- scan: thread t owns bins 4t..4t+3 (words 8t..8t+7, two b128 reads)
  int h[4];
  int ls;
  {
    uint4 a = h4[2 * t];
    uint4 b2 = h4[2 * t + 1];
    h[0] = (int)(a.x + a.y);
    h[1] = (int)(a.z + a.w);
    h[2] = (int)(b2.x + b2.y);
    h[3] = (int)(b2.z + b2.w);
    ls = h[0] + h[1] + h[2] + h[3];
  }
  int s = ls;
#pragma unroll
  for (int off = 1; off < 64; off <<= 1) {
    int o = __shfl_down(s, off);
    if (lane + off < 64) s += o;
  }
  if (lane == 0) wtot[w] = s;
  __syncthreads();  // B2
  int upper = 0;
  for (int w2 = w + 1; w2 < 4; ++w2) upper += wtot[w2];
  int run = (s - ls) + upper;
  int cutbin = -1;
#pragma unroll
  for (int k = 3; k >= 0; --k) {
    if (run < TOPK && run + h[k] >= TOPK) cutbin = (t << 2) + k;
    run += h[k];
  }
  if (cutbin >= 0) s_cut = cutbin;
  __syncthreads();  // B3

  const unsigned int cutbits = (unsigned int)(s_cut + BINOFF) << 18;
  // hist region is DEAD from here (cutbits in registers).

  // ---- compaction: per-lane mask + one wave prefix-scan + one atomic/wave
  unsigned long long msk = 0ull;
  int cnt = 0;
#pragma unroll
  for (int j = 0; j < 36; ++j) {
    unsigned int bits = __float_as_uint(va[j]);
    if (bits >= cutbits) { msk |= 1ull << j; ++cnt; }  // cutbits>0 excludes 0
  }
  int inc = cnt;
#pragma unroll
  for (int off = 1; off < 64; off <<= 1) {
    int o = __shfl_up(inc, off);
    if (lane >= off) inc += o;
  }
  int wtotal = __shfl(inc, 63);
  int wbase = 0;
  if (lane == 63) wbase = atomicAdd(&s_cnt, wtotal);
  wbase = __shfl(wbase, 63);
  int pos = wbase + inc - cnt;
#pragma unroll
  for (int j = 0; j < 36; ++j) {
    if ((msk >> j) & 1ull) {
      if (pos < NCAND) {
        unsigned int bits = __float_as_uint(va[j]);
        int idx = ((t + ((j >> 2) << 8)) << 2) + (j & 3);
        cand[pos] = (((unsigned long long)(~bits)) << 32) | (unsigned int)idx;
      }
      ++pos;
    }
  }
  __syncthreads();  // B4

  const int ncand = s_cnt;
  if (ncand <= 256) {
    // ---- 256-key bitonic, one key per thread; shfl in-wave, LDS for j>=64
    unsigned long long key = cand[t];
#pragma unroll
    for (int k2 = 2; k2 <= 256; k2 <<= 1) {
#pragma unroll
      for (int j = 128; j > 0; j >>= 1) {
        if (j >= k2) continue;
        const bool up = ((t & k2) == 0);
        if (j >= 64) {
          cand[t] = key;
          __syncthreads();
          unsigned long long p = cand[t ^ j];
          key = cex(key, p, up, (t & j) == 0);
          __syncthreads();
        } else {
          unsigned long long p = __shfl_xor(key, j);
          key = cex(key, p, up, (lane & j) == 0);
        }
      }
    }
    if (t < TOPK) skey[t] = key;
  } else {
    // ---- rare fallback: block-wide LDS bitonic over 512
    int NS = 512;
    for (int k2 = 2; k2 <= NS; k2 <<= 1) {
      for (int j = k2 >> 1; j > 0; j >>= 1) {
        if (j >= 128) {
          __syncthreads();
          for (int p = t; p < NS; p += 256) {
            int ixj = p ^ j;
            if (ixj > p) {
              unsigned long long a = cand[p], c2 = cand[ixj];
              bool up = ((p & k2) == 0);
              if (up ? (a > c2) : (a < c2)) { cand[p] = c2; cand[ixj] = a; }
            }
          }
          __syncthreads();
        } else {
          int base = w << 7;
          if (base < NS) {
#pragma unroll
            for (int half = 0; half < 2; ++half) {
              int p = base + lane + (half << 6);
              int ixj = p ^ j;
              if (ixj > p) {
                unsigned long long a = cand[p], c2 = cand[ixj];
                bool up = ((p & k2) == 0);
                if (up ? (a > c2) : (a < c2)) { cand[p] = c2; cand[ixj] = a; }
              }
            }
          }
        }
      }
    }
    __syncthreads();
    if (t < TOPK) skey[t] = cand[t];
  }
  __syncthreads();  // skey ready; cand & hist regions now free for overlays

  // ======================= FUSED NMS (k3 logic) ==========================
  typedef unsigned long long ull;
  float4* lbox  = (float4*)cand;                    // 1600 B (cand region)
  float*  larea = (float*)((char*)cand + 1600);     //  400 B
  float*  lscore= (float*)((char*)cand + 2000);     //  400 B
  ull*    pmbuf = (ull*)hist;                       // 6144 B (hist region)
  ull*    keepw = (ull*)((char*)hist + 6144);       //   16 B

  // ---- phase 1: stage rows 0..99 (decode boxes from loc/priors gather)
  if (t < TOPK) {
    ull key2 = skey[t];
    float sv = __uint_as_float(~(unsigned int)(key2 >> 32));
    int idx = (int)(key2 & 0xFFFFFFFFull);
    if ((unsigned)idx >= NPRIORS) { idx = 0; sv = 0.f; }
    float4 bx = decode_box(((const float4*)loc)[(size_t)b * NPRIORS + idx],
                           ((const float4*)priors)[idx]);
    lbox[t] = bx;
    larea[t] = fmaxf(bx.z - bx.x, 0.f) * fmaxf(bx.w - bx.y, 0.f);
    lscore[t] = sv;
  }
  __syncthreads();

  // per-lane row data (rows A=lane, B=lane+64)
  const bool hasb = (lane + 64) < TOPK;
  float4 ba = lbox[lane];
  float aa = larea[lane];
  float4 bb2 = lbox[hasb ? (lane + 64) : 0];
  float ab = larea[hasb ? (lane + 64) : 0];

  // ---- phase 2: partial masks for j in this wave's quartile
  ull ra0 = 0, ra1 = 0, rb1 = 0;
  int jlo = max(1, w * 25);
  int jhi = min(TOPK, w * 25 + 25);
  for (int j = jlo; j < jhi; ++j) {
    float4 bj = lbox[j];      // uniform address -> broadcast
    float aj = larea[j];
    if (lane < j) {
      float iw = fmaxf(fminf(ba.z, bj.z) - fmaxf(ba.x, bj.x), 0.f);
      float ih = fmaxf(fminf(ba.w, bj.w) - fmaxf(ba.y, bj.y), 0.f);
      float inter = iw * ih;
      float iou = inter / (aa + aj - inter + 1e-9f);
      if (iou > 0.45f) {
        if (j < 64) ra0 |= 1ull << j; else ra1 |= 1ull << (j - 64);
      }
    }
    if (hasb && (lane + 64) < j) {   // j is then >= 65 -> upper half
      float iw = fmaxf(fminf(bb2.z, bj.z) - fmaxf(bb2.x, bj.x), 0.f);
      float ih = fmaxf(fminf(bb2.w, bj.w) - fmaxf(bb2.y, bj.y), 0.f);
      float inter = iw * ih;
      float iou = inter / (ab + aj - inter + 1e-9f);
      if (iou > 0.45f) rb1 |= 1ull << (j - 64);
    }
  }
  pmbuf[((w << 6) + lane) * 3 + 0] = ra0;
  pmbuf[((w << 6) + lane) * 3 + 1] = ra1;
  pmbuf[((w << 6) + lane) * 3 + 2] = rb1;
  __syncthreads();

  // ---- phase 3: wave 0 combines + propagates
  if (w == 0) {
    ull fa0 = pmbuf[lane * 3 + 0] | pmbuf[(64 + lane) * 3 + 0] |
              pmbuf[(128 + lane) * 3 + 0] | pmbuf[(192 + lane) * 3 + 0];
    ull fa1 = pmbuf[lane * 3 + 1] | pmbuf[(64 + lane) * 3 + 1] |
              pmbuf[(128 + lane) * 3 + 1] | pmbuf[(192 + lane) * 3 + 1];
    ull fb1 = pmbuf[lane * 3 + 2] | pmbuf[(64 + lane) * 3 + 2] |
              pmbuf[(128 + lane) * 3 + 2] | pmbuf[(192 + lane) * 3 + 2];

    float sva = lscore[lane];
    float svb = hasb ? lscore[lane + 64] : 0.f;
    ull keep0 = __ballot(sva > 0.01f);
    ull keep1 = __ballot(hasb && (svb > 0.01f));
    for (int i = 0; i < TOPK; ++i) {
      bool il = i < 64;
      bool kb = il ? ((keep0 >> i) & 1ull) : ((keep1 >> (i - 64)) & 1ull);
      ull m0 = __shfl(il ? fa0 : 0ull, i & 63);
      ull m1 = __shfl(il ? fa1 : fb1, i & 63);
      if (kb) { keep0 &= ~m0; keep1 &= ~m1; }
    }
    if (lane == 0) { keepw[0] = keep0; keepw[1] = keep1; }
  }
  __syncthreads();

  // ---- outputs (threads 0..99)
  if (t < TOPK) {
    bool kp = (t < 64) ? ((keepw[0] >> t) & 1ull)
                       : ((keepw[1] >> (t - 64)) & 1ull);
    s_k[(size_t)bc * TOPK + t] = kp ? lscore[t] : 0.f;
    ((float4*)(b_k + (size_t)bc * TOPK * 4))[t] = lbox[t];
  }

  // =============== last-block-per-batch: final top-100 (k4) ==============
  __syncthreads();   // barrier drains vmcnt -> this block's stores complete
  if (t == 0) {
    __threadfence();                               // release (L2 writeback)
    s_last = (int)(atomicAdd(&done[b], 1u) == (unsigned)(NC1 - 1));
  }
  __syncthreads();
  if (!s_last) return;
  if (t == 0) __threadfence();                     // acquire (invalidate)
  __syncthreads();

  {
    const float4* src4 = (const float4*)(s_k + (size_t)b * FLATC);

    // re-init hist/cand/counters (overlays dead)
    h4[t] = z4;
    h4[t + 256] = z4;
    cand[t] = ~0ull;
    cand[t + 256] = ~0ull;
    if (t == 0) { s_cnt = 0; s_cut = 0; }
    __syncthreads();

    // pass 1: histogram (two-pass keeps VGPR low on this cold path)
    for (int i = 0; i < 8; ++i) {
      int p = t + (i << 8);
      if (p < FV4) {
        float4 v = src4[p];
        float vv[4] = {v.x, v.y, v.z, v.w};
#pragma unroll
        for (int cc2 = 0; cc2 < 4; ++cc2) {
          unsigned int bits = __float_as_uint(vv[cc2]);
          if (bits != 0u) {
            int bin = (int)(bits >> 18) - BINOFF;
            bin = max(0, min(NBIN - 1, bin));
            atomicAdd(&hist[(bin << 1) | (lane & 1)], 1u);
          }
        }
      }
    }
    __syncthreads();

    int h2[4];
    int ls2;
    {
      uint4 a = h4[2 * t];
      uint4 b2 = h4[2 * t + 1];
      h2[0] = (int)(a.x + a.y);
      h2[1] = (int)(a.z + a.w);
      h2[2] = (int)(b2.x + b2.y);
      h2[3] = (int)(b2.z + b2.w);
      ls2 = h2[0] + h2[1] + h2[2] + h2[3];
    }
    int s2 = ls2;
#pragma unroll
    for (int off = 1; off < 64; off <<= 1) {
      int o = __shfl_down(s2, off);
      if (lane + off < 64) s2 += o;
    }
    if (lane == 0) wtot[w] = s2;
    __syncthreads();
    int upper2 = 0;
    for (int w2 = w + 1; w2 < 4; ++w2) upper2 += wtot[w2];
    int run2 = (s2 - ls2) + upper2;
    int cutbin2 = -1;
#pragma unroll
    for (int k = 3; k >= 0; --k) {
      if (run2 < TOPK && run2 + h2[k] >= TOPK) cutbin2 = (t << 2) + k;
      run2 += h2[k];
    }
    if (cutbin2 >= 0) s_cut = cutbin2;
    __syncthreads();

    const unsigned int cutb4 = (unsigned int)(s_cut + BINOFF) << 18;

    // pass 2: compact (ballot form; cost irrelevant at 1 block/batch)
    for (int i = 0; i < 8; ++i) {
      int p = t + (i << 8);
      bool inb = (p < FV4);
      float4 v = make_float4(0.f, 0.f, 0.f, 0.f);
      if (inb) v = src4[p];
      float vv[4] = {v.x, v.y, v.z, v.w};
#pragma unroll
      for (int cc2 = 0; cc2 < 4; ++cc2) {
        unsigned int bits = __float_as_uint(vv[cc2]);
        bool pred = inb && (bits >= cutb4);
        unsigned long long mB = __ballot(pred);
        if (mB) {
          int base = 0;
          if (lane == 0) base = atomicAdd(&s_cnt, (int)__popcll(mB));
          base = __shfl(base, 0);
          if (pred) {
            int pos2 = base + (int)__popcll(mB & ((1ull << lane) - 1ull));
            if (pos2 < NCAND)
              cand[pos2] = (((unsigned long long)(~bits)) << 32) |
                           (unsigned int)((p << 2) + cc2);
          }
        }
      }
    }
    __syncthreads();

    const int nc4 = s_cnt;
    unsigned long long okey;
    if (nc4 <= 256) {
      unsigned long long key = cand[t];
#pragma unroll
      for (int k2 = 2; k2 <= 256; k2 <<= 1) {
#pragma unroll
        for (int j = 128; j > 0; j >>= 1) {
          if (j >= k2) continue;
          const bool up = ((t & k2) == 0);
          if (j >= 64) {
            cand[t] = key;
            __syncthreads();
            unsigned long long p = cand[t ^ j];
            key = cex(key, p, up, (t & j) == 0);
            __syncthreads();
          } else {
            unsigned long long p = __shfl_xor(key, j);
            key = cex(key, p, up, (lane & j) == 0);
          }
        }
      }
      okey = key;
    } else {
      int NS = 512;
      for (int k2 = 2; k2 <= NS; k2 <<= 1) {
        for (int j = k2 >> 1; j > 0; j >>= 1) {
          if (j >= 128) {
            __syncthreads();
            for (int p = t; p < NS; p += 256) {
              int ixj = p ^ j;
              if (ixj > p) {
                unsigned long long a = cand[p], c2 = cand[ixj];
                bool up = ((p & k2) == 0);
                if (up ? (a > c2) : (a < c2)) { cand[p] = c2; cand[ixj] = a; }
              }
            }
            __syncthreads();
          } else {
            int base = w << 7;
            if (base < NS) {
#pragma unroll
              for (int half = 0; half < 2; ++half) {
                int p = base + lane + (half << 6);
                int ixj = p ^ j;
                if (ixj > p) {
                  unsigned long long a = cand[p], c2 = cand[ixj];
                  bool up = ((p & k2) == 0);
                  if (up ? (a > c2) : (a < c2)) { cand[p] = c2; cand[ixj] = a; }
                }
              }
            }
          }
        }
      }
      __syncthreads();
      okey = cand[min(t, NCAND - 1)];
    }

    if (t < MAXDET) {
      unsigned long long key = okey;
      unsigned int vb = ~(unsigned int)(key >> 32);
      float sv = __uint_as_float(vb);
      int f = (int)(key & 0xFFFFFFFFull);
      if ((unsigned)f >= FLATC) { f = 0; sv = 0.f; }
      float4 bb = *(const float4*)(b_k + ((size_t)b * FLATC + f) * 4);
      ((float4*)out)[b * MAXDET + t] = bb;
      out[BATCH * MAXDET * 4 + b * MAXDET + t] = sv;
      int cls = f / TOPK + 1;
      out[BATCH * MAXDET * 5 + b * MAXDET + t] = (float)cls;
    }
  }
}

// ---------------------------------------------------------------------------
extern "C" void kernel_launch(void* const* d_in, const int* in_sizes, int n_in,
                              void* d_out, int out_size, void* d_ws,
                              size_t ws_size, hipStream_t stream) {
  const float* cls_logits = (const float*)d_in[0];
  const float* bbox_pred  = (const float*)d_in[1];
  const float* priors     = (const float*)d_in[2];
  float* out = (float*)d_out;

  float* scores_t = (float*)d_ws;                          // [B][NT][80][64]
  float* s_k = scores_t + (size_t)BATCH * NT * NC1 * 64;   // [2560][100]
  float* b_k = s_k + (size_t)BATCH * NC1 * TOPK;           // [2560][100][4]
  unsigned int* done = (unsigned int*)(b_k + (size_t)BATCH * NC1 * TOPK * 4);

  softmax_transpose_kernel<<<BATCH * NT, 256, 0, stream>>>(cls_logits,
                                                           scores_t, done);
  topk_nms_kernel<<<BATCH * NC1, 256, 0, stream>>>(scores_t, bbox_pred,
                                                   priors, s_k, b_k, out,
                                                   done);
}

// Round 12
// 100.664 us; speedup vs baseline: 1.6655x; 1.6655x over previous
//
#include <hip/hip_runtime.h>
#include <hip/hip_bf16.h>
#include <float.h>

#define BATCH    32
#define NPRIORS  8732
#define NT       137            // tiles of 64 priors
#define NPAD     (NT * 64)      // 8768 (padded prior count)
#define NV4T     (NPAD / 4)     // 2192 float4 per class column
#define NCLASSES 81
#define NC1      80             // classes excluding background
#define TOPK     100
#define MAXDET   100
#define FLATC    (NC1 * TOPK)   // 8000
#define FV4      2000           // FLATC / 4
#define NCAND    512
#define NBIN     1024           // (bits>>18) - 3040 : exp + 5 mantissa bits
#define BINOFF   3040

// ---------------------------------------------------------------------------
// Kernel 1: softmax over classes + TILED transpose.  (v5 verbatim — proven)
//   direct quad-cooperative loads, register softmax, LDS transpose at column
//   stride 80 (<=2-way banks), ONE barrier, 1280 contiguous float4 flush.
// scores_t layout: [B][NT][NC1][64] (tile-major).
// ---------------------------------------------------------------------------
__global__ __launch_bounds__(256) void softmax_transpose_kernel(
    const float* __restrict__ logits, float* __restrict__ scores_t) {
  int b = blockIdx.x / NT;
  int tile = blockIdx.x - b * NT;
  int n0 = tile * 64;
  int rows = min(64, NPRIORS - n0);  // 64 or 28

  int t = threadIdx.x;
  int r = t >> 2;   // row within tile
  int q = t & 3;

  __shared__ __align__(16) float lds[NC1 * 80];  // 25.6 KB transpose buffer

  const bool live = (r < rows);

  float v[21];
  float s = 0.f;
  if (live) {
    const float* rowp = logits + ((size_t)b * NPRIORS + n0 + r) * NCLASSES;
#pragma unroll
    for (int k = 0; k < 20; ++k) v[k] = rowp[q + (k << 2)];
    v[20] = (q == 0) ? rowp[80] : -FLT_MAX;

    float m = -FLT_MAX;
#pragma unroll
    for (int k = 0; k < 20; ++k) m = fmaxf(m, v[k]);
    if (q == 0) m = fmaxf(m, v[20]);
    m = fmaxf(m, __shfl_xor(m, 1));
    m = fmaxf(m, __shfl_xor(m, 2));

#pragma unroll
    for (int k = 0; k < 20; ++k) {
      v[k] = expf(v[k] - m);
      s += v[k];
    }
    if (q == 0) {
      v[20] = expf(v[20] - m);
      s += v[20];
    }
    s += __shfl_xor(s, 1);
    s += __shfl_xor(s, 2);

    // transposed store into LDS, column stride 80 (<=2-way banks)
#pragma unroll
    for (int k = 0; k < 20; ++k) {
      int c = q + (k << 2);
      if (c >= 1) lds[(c - 1) * 80 + r] = v[k] / s;
    }
    if (q == 0) lds[79 * 80 + r] = v[20] / s;
  } else {
    // pad slots must be +0.0 (bits==0 -> never histogrammed/selected)
#pragma unroll
    for (int k = 0; k < 20; ++k) {
      int c = q + (k << 2);
      if (c >= 1) lds[(c - 1) * 80 + r] = 0.f;
    }
    if (q == 0) lds[79 * 80 + r] = 0.f;
  }
  __syncthreads();  // transposed tile ready

  // ---- flush: 1280 contiguous float4 stores
  float4* d4 = (float4*)(scores_t + (size_t)(b * NT + tile) * (NC1 * 64));
#pragma unroll
  for (int i = 0; i < 5; ++i) {
    int o4 = t + (i << 8);       // 0..1279
    int c = o4 >> 4;             // class column 0..79
    int j = o4 & 15;             // float4 within column
    d4[o4] = *(const float4*)&lds[c * 80 + (j << 2)];
  }
}

// ---------------------------------------------------------------------------
// Box decode (identical float expressions to the reference)
// ---------------------------------------------------------------------------
__device__ __forceinline__ float4 decode_box(float4 l, float4 p) {
  float cx = l.x * 0.1f * p.z + p.x;
  float cy = l.y * 0.1f * p.w + p.y;
  float w  = expf(l.z * 0.2f) * p.z;
  float h  = expf(l.w * 0.2f) * p.w;
  return make_float4(cx - w * 0.5f, cy - h * 0.5f, cx + w * 0.5f,
                     cy + h * 0.5f);
}

__device__ __forceinline__ unsigned long long cex(unsigned long long key,
                                                  unsigned long long p,
                                                  bool up, bool low) {
  return (up == low) ? (key < p ? key : p) : (key > p ? key : p);
}

// ---------------------------------------------------------------------------
// Kernel 2: block-per-(batch,class) top-100 select + FUSED NMS.
// v11 (best measured: 100.9 us total): selection machinery is v5/v3 verbatim
//      (fp32 scores_t single read, 2-replica hist, coarse cut, mask
//      compaction, 256-key hybrid sort), then the NMS phases run in-block on
//      the sorted top-100 (LDS overlays on dead hist/cand regions).
//      NO device-scope fences (v12's per-block __threadfence cost +67 us).
// ---------------------------------------------------------------------------
__global__ __launch_bounds__(256, 8) void topk_nms_kernel(
    const float* __restrict__ scores_t, const float* __restrict__ loc,
    const float* __restrict__ priors, float* __restrict__ s_k,
    float* __restrict__ b_k) {
  const int bc = blockIdx.x;
  const int b = bc / NC1;
  const int c = bc - b * NC1;
  const int t = threadIdx.x;
  const int lane = t & 63;
  const int w = t >> 6;

  __shared__ __align__(16) unsigned int hist[NBIN * 2];     // 8 KB, 2 replicas
  __shared__ __align__(16) unsigned long long cand[NCAND];  // 4 KB
  __shared__ __align__(16) unsigned long long skey[TOPK];   // 800 B sorted keys
  __shared__ int s_cnt, s_cut, wtot[4];

  const float4* s4 = (const float4*)scores_t;
  const size_t base4 = (size_t)b * (NT * NC1 * 16) + (size_t)c * 16;

  // ---- single global read: 9 float4 = 36 floats into registers
  float va[36];
#pragma unroll
  for (int i = 0; i < 9; ++i) {
    int p = t + (i << 8);
    float4 v = make_float4(0.f, 0.f, 0.f, 0.f);
    if (p < NV4T) v = s4[base4 + (size_t)(p >> 4) * (NC1 * 16) + (p & 15)];
    va[4 * i + 0] = v.x; va[4 * i + 1] = v.y;
    va[4 * i + 2] = v.z; va[4 * i + 3] = v.w;
  }
#pragma unroll
  for (int j = 0; j < 36; ++j) asm volatile("" : "+v"(va[j]));  // pin live

  // ---- zero hist (2048 words) + init cand + counters
  uint4* h4 = (uint4*)hist;
  const uint4 z4 = make_uint4(0u, 0u, 0u, 0u);
  h4[t] = z4;
  h4[t + 256] = z4;
  cand[t] = ~0ull;
  cand[t + 256] = ~0ull;
  if (t == 0) { s_cnt = 0; s_cut = 0; }
  __syncthreads();  // B0

  // ---- coarse histogram from registers (skip zeros: padding & exact-0)
#pragma unroll
  for (int j = 0; j < 36; ++j) {
    unsigned int bits = __float_as_uint(va[j]);
    if (bits != 0u) {
      int bin = (int)(bits >> 18) - BINOFF;
      bin = max(0, min(NBIN - 1, bin));
      atomicAdd(&hist[(bin << 1) | (lane & 1)], 1u);
    }
  }
  __syncthreads();  // B1

  // ---- scan: thread t owns bins 4t..4t+3 (words 8t..8t+7, two b128 reads)
  int h[4];
  int ls;
  {
    uint4 a = h4[2 * t];
    uint4 b2 = h4[2 * t + 1];
    h[0] = (int)(a.x + a.y);
    h[1] = (int)(a.z + a.w);
    h[2] = (int)(b2.x + b2.y);
    h[3] = (int)(b2.z + b2.w);
    ls = h[0] + h[1] + h[2] + h[3];
  }
  int s = ls;
#pragma unroll
  for (int off = 1; off < 64; off <<= 1) {
    int o = __shfl_down(s, off);
    if (lane + off < 64) s += o;
  }
  if (lane == 0) wtot[w] = s;
  __syncthreads();  // B2
  int upper = 0;
  for (int w2 = w + 1; w2 < 4; ++w2) upper += wtot[w2];
  int run = (s - ls) + upper;
  int cutbin = -1;
#pragma unroll
  for (int k = 3; k >= 0; --k) {
    if (run < TOPK && run + h[k] >= TOPK) cutbin = (t << 2) + k;
    run += h[k];
  }
  if (cutbin >= 0) s_cut = cutbin;
  __syncthreads();  // B3

  const unsigned int cutbits = (unsigned int)(s_cut + BINOFF) << 18;
  // hist region is DEAD from here (cutbits in registers).

  // ---- compaction: per-lane mask + one wave prefix-scan + one atomic/wave
  unsigned long long msk = 0ull;
  int cnt = 0;
#pragma unroll
  for (int j = 0; j < 36; ++j) {
    unsigned int bits = __float_as_uint(va[j]);
    if (bits >= cutbits) { msk |= 1ull << j; ++cnt; }  // cutbits>0 excludes 0
  }
  int inc = cnt;
#pragma unroll
  for (int off = 1; off < 64; off <<= 1) {
    int o = __shfl_up(inc, off);
    if (lane >= off) inc += o;
  }
  int wtotal = __shfl(inc, 63);
  int wbase = 0;
  if (lane == 63) wbase = atomicAdd(&s_cnt, wtotal);
  wbase = __shfl(wbase, 63);
  int pos = wbase + inc - cnt;
#pragma unroll
  for (int j = 0; j < 36; ++j) {
    if ((msk >> j) & 1ull) {
      if (pos < NCAND) {
        unsigned int bits = __float_as_uint(va[j]);
        int idx = ((t + ((j >> 2) << 8)) << 2) + (j & 3);
        cand[pos] = (((unsigned long long)(~bits)) << 32) | (unsigned int)idx;
      }
      ++pos;
    }
  }
  __syncthreads();  // B4

  const int ncand = s_cnt;
  if (ncand <= 256) {
    // ---- 256-key bitonic, one key per thread; shfl in-wave, LDS for j>=64
    unsigned long long key = cand[t];
#pragma unroll
    for (int k2 = 2; k2 <= 256; k2 <<= 1) {
#pragma unroll
      for (int j = 128; j > 0; j >>= 1) {
        if (j >= k2) continue;
        const bool up = ((t & k2) == 0);
        if (j >= 64) {
          cand[t] = key;
          __syncthreads();
          unsigned long long p = cand[t ^ j];
          key = cex(key, p, up, (t & j) == 0);
          __syncthreads();
        } else {
          unsigned long long p = __shfl_xor(key, j);
          key = cex(key, p, up, (lane & j) == 0);
        }
      }
    }
    if (t < TOPK) skey[t] = key;
  } else {
    // ---- rare fallback: block-wide LDS bitonic over 512
    int NS = 512;
    for (int k2 = 2; k2 <= NS; k2 <<= 1) {
      for (int j = k2 >> 1; j > 0; j >>= 1) {
        if (j >= 128) {
          __syncthreads();
          for (int p = t; p < NS; p += 256) {
            int ixj = p ^ j;
            if (ixj > p) {
              unsigned long long a = cand[p], c2 = cand[ixj];
              bool up = ((p & k2) == 0);
              if (up ? (a > c2) : (a < c2)) { cand[p] = c2; cand[ixj] = a; }
            }
          }
          __syncthreads();
        } else {
          int base = w << 7;
          if (base < NS) {
#pragma unroll
            for (int half = 0; half < 2; ++half) {
              int p = base + lane + (half << 6);
              int ixj = p ^ j;
              if (ixj > p) {
                unsigned long long a = cand[p], c2 = cand[ixj];
                bool up = ((p & k2) == 0);
                if (up ? (a > c2) : (a < c2)) { cand[p] = c2; cand[ixj] = a; }
              }
            }
          }
        }
      }
    }
    __syncthreads();
    if (t < TOPK) skey[t] = cand[t];
  }
  __syncthreads();  // skey ready; cand & hist regions now free for overlays

  // ======================= FUSED NMS (k3 logic) ==========================
  typedef unsigned long long ull;
  float4* lbox  = (float4*)cand;                    // 1600 B (cand region)
  float*  larea = (float*)((char*)cand + 1600);     //  400 B
  float*  lscore= (float*)((char*)cand + 2000);     //  400 B
  ull*    pmbuf = (ull*)hist;                       // 6144 B (hist region)
  ull*    keepw = (ull*)((char*)hist + 6144);       //   16 B

  // ---- phase 1: stage rows 0..99 (decode boxes from loc/priors gather)
  if (t < TOPK) {
    ull key2 = skey[t];
    float sv = __uint_as_float(~(unsigned int)(key2 >> 32));
    int idx = (int)(key2 & 0xFFFFFFFFull);
    if ((unsigned)idx >= NPRIORS) { idx = 0; sv = 0.f; }
    float4 bx = decode_box(((const float4*)loc)[(size_t)b * NPRIORS + idx],
                           ((const float4*)priors)[idx]);
    lbox[t] = bx;
    larea[t] = fmaxf(bx.z - bx.x, 0.f) * fmaxf(bx.w - bx.y, 0.f);
    lscore[t] = sv;
  }
  __syncthreads();

  // per-lane row data (rows A=lane, B=lane+64)
  const bool hasb = (lane + 64) < TOPK;
  float4 ba = lbox[lane];
  float aa = larea[lane];
  float4 bb2 = lbox[hasb ? (lane + 64) : 0];
  float ab = larea[hasb ? (lane + 64) : 0];

  // ---- phase 2: partial masks for j in this wave's quartile
  ull ra0 = 0, ra1 = 0, rb1 = 0;
  int jlo = max(1, w * 25);
  int jhi = min(TOPK, w * 25 + 25);
  for (int j = jlo; j < jhi; ++j) {
    float4 bj = lbox[j];      // uniform address -> broadcast
    float aj = larea[j];
    if (lane < j) {
      float iw = fmaxf(fminf(ba.z, bj.z) - fmaxf(ba.x, bj.x), 0.f);
      float ih = fmaxf(fminf(ba.w, bj.w) - fmaxf(ba.y, bj.y), 0.f);
      float inter = iw * ih;
      float iou = inter / (aa + aj - inter + 1e-9f);
      if (iou > 0.45f) {
        if (j < 64) ra0 |= 1ull << j; else ra1 |= 1ull << (j - 64);
      }
    }
    if (hasb && (lane + 64) < j) {   // j is then >= 65 -> upper half
      float iw = fmaxf(fminf(bb2.z, bj.z) - fmaxf(bb2.x, bj.x), 0.f);
      float ih = fmaxf(fminf(bb2.w, bj.w) - fmaxf(bb2.y, bj.y), 0.f);
      float inter = iw * ih;
      float iou = inter / (ab + aj - inter + 1e-9f);
      if (iou > 0.45f) rb1 |= 1ull << (j - 64);
    }
  }
  pmbuf[((w << 6) + lane) * 3 + 0] = ra0;
  pmbuf[((w << 6) + lane) * 3 + 1] = ra1;
  pmbuf[((w << 6) + lane) * 3 + 2] = rb1;
  __syncthreads();

  // ---- phase 3: wave 0 combines + propagates
  if (w == 0) {
    ull fa0 = pmbuf[lane * 3 + 0] | pmbuf[(64 + lane) * 3 + 0] |
              pmbuf[(128 + lane) * 3 + 0] | pmbuf[(192 + lane) * 3 + 0];
    ull fa1 = pmbuf[lane * 3 + 1] | pmbuf[(64 + lane) * 3 + 1] |
              pmbuf[(128 + lane) * 3 + 1] | pmbuf[(192 + lane) * 3 + 1];
    ull fb1 = pmbuf[lane * 3 + 2] | pmbuf[(64 + lane) * 3 + 2] |
              pmbuf[(128 + lane) * 3 + 2] | pmbuf[(192 + lane) * 3 + 2];

    float sva = lscore[lane];
    float svb = hasb ? lscore[lane + 64] : 0.f;
    ull keep0 = __ballot(sva > 0.01f);
    ull keep1 = __ballot(hasb && (svb > 0.01f));
    for (int i = 0; i < TOPK; ++i) {
      bool il = i < 64;
      bool kb = il ? ((keep0 >> i) & 1ull) : ((keep1 >> (i - 64)) & 1ull);
      ull m0 = __shfl(il ? fa0 : 0ull, i & 63);
      ull m1 = __shfl(il ? fa1 : fb1, i & 63);
      if (kb) { keep0 &= ~m0; keep1 &= ~m1; }
    }
    if (lane == 0) { keepw[0] = keep0; keepw[1] = keep1; }
  }
  __syncthreads();

  // ---- outputs (threads 0..99)
  if (t < TOPK) {
    bool kp = (t < 64) ? ((keepw[0] >> t) & 1ull)
                       : ((keepw[1] >> (t - 64)) & 1ull);
    s_k[(size_t)bc * TOPK + t] = kp ? lscore[t] : 0.f;
    ((float4*)(b_k + (size_t)bc * TOPK * 4))[t] = lbox[t];
  }
}

// ---------------------------------------------------------------------------
// Kernel 4: per-image exact top-100 over 8000 candidates.  (v5 verbatim)
// out layout: boxes[32][100][4] | scores[32][100] | labels[32][100] (as f32)
// ---------------------------------------------------------------------------
__global__ __launch_bounds__(256) void final_topk_kernel(
    const float* __restrict__ s_k, const float* __restrict__ b_k,
    float* __restrict__ out) {
  const int b = blockIdx.x;
  const int t = threadIdx.x;
  const int lane = t & 63;
  const int w = t >> 6;

  __shared__ __align__(16) unsigned int hist[NBIN * 2];
  __shared__ __align__(16) unsigned long long cand[NCAND];
  __shared__ int s_cnt, s_cut, wtot[4];

  const float4* src4 = (const float4*)(s_k + (size_t)b * FLATC);

  float va[32];
#pragma unroll
  for (int i = 0; i < 8; ++i) {
    int p = t + (i << 8);
    float4 v = make_float4(0.f, 0.f, 0.f, 0.f);
    if (p < FV4) v = src4[p];
    va[4 * i + 0] = v.x; va[4 * i + 1] = v.y;
    va[4 * i + 2] = v.z; va[4 * i + 3] = v.w;
  }

  uint4* h4 = (uint4*)hist;
  const uint4 z4 = make_uint4(0u, 0u, 0u, 0u);
  h4[t] = z4;
  h4[t + 256] = z4;
  cand[t] = ~0ull;
  cand[t + 256] = ~0ull;
  if (t == 0) { s_cnt = 0; s_cut = 0; }
  __syncthreads();

#pragma unroll
  for (int j = 0; j < 32; ++j) {
    unsigned int bits = __float_as_uint(va[j]);
    if (bits != 0u) {
      int bin = (int)(bits >> 18) - BINOFF;
      bin = max(0, min(NBIN - 1, bin));
      atomicAdd(&hist[(bin << 1) | (lane & 1)], 1u);
    }
  }
  __syncthreads();

  int h[4];
  int ls;
  {
    uint4 a = h4[2 * t];
    uint4 b2 = h4[2 * t + 1];
    h[0] = (int)(a.x + a.y);
    h[1] = (int)(a.z + a.w);
    h[2] = (int)(b2.x + b2.y);
    h[3] = (int)(b2.z + b2.w);
    ls = h[0] + h[1] + h[2] + h[3];
  }
  int s = ls;
#pragma unroll
  for (int off = 1; off < 64; off <<= 1) {
    int o = __shfl_down(s, off);
    if (lane + off < 64) s += o;
  }
  if (lane == 0) wtot[w] = s;
  __syncthreads();
  int upper = 0;
  for (int w2 = w + 1; w2 < 4; ++w2) upper += wtot[w2];
  int run = (s - ls) + upper;
  int cutbin = -1;
#pragma unroll
  for (int k = 3; k >= 0; --k) {
    if (run < TOPK && run + h[k] >= TOPK) cutbin = (t << 2) + k;
    run += h[k];
  }
  if (cutbin >= 0) s_cut = cutbin;
  __syncthreads();

  const unsigned int cutbits = (unsigned int)(s_cut + BINOFF) << 18;

  unsigned int msk = 0u;
  int cnt = 0;
#pragma unroll
  for (int j = 0; j < 32; ++j) {
    unsigned int bits = __float_as_uint(va[j]);
    if (bits >= cutbits) { msk |= 1u << j; ++cnt; }
  }
  int inc = cnt;
#pragma unroll
  for (int off = 1; off < 64; off <<= 1) {
    int o = __shfl_up(inc, off);
    if (lane >= off) inc += o;
  }
  int wtotal = __shfl(inc, 63);
  int wbase = 0;
  if (lane == 63) wbase = atomicAdd(&s_cnt, wtotal);
  wbase = __shfl(wbase, 63);
  int pos = wbase + inc - cnt;
#pragma unroll
  for (int j = 0; j < 32; ++j) {
    if ((msk >> j) & 1u) {
      if (pos < NCAND) {
        unsigned int bits = __float_as_uint(va[j]);
        int idx = ((t + ((j >> 2) << 8)) << 2) + (j & 3);
        cand[pos] = (((unsigned long long)(~bits)) << 32) | (unsigned int)idx;
      }
      ++pos;
    }
  }
  __syncthreads();

  const int ncand = s_cnt;
  unsigned long long okey;
  if (ncand <= 256) {
    unsigned long long key = cand[t];
#pragma unroll
    for (int k2 = 2; k2 <= 256; k2 <<= 1) {
#pragma unroll
      for (int j = 128; j > 0; j >>= 1) {
        if (j >= k2) continue;
        const bool up = ((t & k2) == 0);
        if (j >= 64) {
          cand[t] = key;
          __syncthreads();
          unsigned long long p = cand[t ^ j];
          key = cex(key, p, up, (t & j) == 0);
          __syncthreads();
        } else {
          unsigned long long p = __shfl_xor(key, j);
          key = cex(key, p, up, (lane & j) == 0);
        }
      }
    }
    okey = key;
  } else {
    int NS = 512;
    for (int k2 = 2; k2 <= NS; k2 <<= 1) {
      for (int j = k2 >> 1; j > 0; j >>= 1) {
        if (j >= 128) {
          __syncthreads();
          for (int p = t; p < NS; p += 256) {
            int ixj = p ^ j;
            if (ixj > p) {
              unsigned long long a = cand[p], c2 = cand[ixj];
              bool up = ((p & k2) == 0);
              if (up ? (a > c2) : (a < c2)) { cand[p] = c2; cand[ixj] = a; }
            }
          }
          __syncthreads();
        } else {
          int base = w << 7;
          if (base < NS) {
#pragma unroll
            for (int half = 0; half < 2; ++half) {
              int p = base + lane + (half << 6);
              int ixj = p ^ j;
              if (ixj > p) {
                unsigned long long a = cand[p], c2 = cand[ixj];
                bool up = ((p & k2) == 0);
                if (up ? (a > c2) : (a < c2)) { cand[p] = c2; cand[ixj] = a; }
              }
            }
          }
        }
      }
    }
    __syncthreads();
    okey = cand[min(t, NCAND - 1)];
  }

  if (t < MAXDET) {
    unsigned long long key = okey;
    unsigned int vb = ~(unsigned int)(key >> 32);
    float sv = __uint_as_float(vb);
    int f = (int)(key & 0xFFFFFFFFull);
    if ((unsigned)f >= FLATC) { f = 0; sv = 0.f; }
    float4 bb = *(const float4*)(b_k + ((size_t)b * FLATC + f) * 4);
    ((float4*)out)[b * MAXDET + t] = bb;
    out[BATCH * MAXDET * 4 + b * MAXDET + t] = sv;
    int cls = f / TOPK + 1;
    out[BATCH * MAXDET * 5 + b * MAXDET + t] = (float)cls;
  }
}

// ---------------------------------------------------------------------------
extern "C" void kernel_launch(void* const* d_in, const int* in_sizes, int n_in,
                              void* d_out, int out_size, void* d_ws,
                              size_t ws_size, hipStream_t stream) {
  const float* cls_logits = (const float*)d_in[0];
  const float* bbox_pred  = (const float*)d_in[1];
  const float* priors     = (const float*)d_in[2];
  float* out = (float*)d_out;

  float* scores_t = (float*)d_ws;                          // [B][NT][80][64]
  float* s_k = scores_t + (size_t)BATCH * NT * NC1 * 64;   // [2560][100]
  float* b_k = s_k + (size_t)BATCH * NC1 * TOPK;           // [2560][100][4]

  softmax_transpose_kernel<<<BATCH * NT, 256, 0, stream>>>(cls_logits,
                                                           scores_t);
  topk_nms_kernel<<<BATCH * NC1, 256, 0, stream>>>(scores_t, bbox_pred,
                                                   priors, s_k, b_k);
  final_topk_kernel<<<BATCH, 256, 0, stream>>>(s_k, b_k, out);
}